// Round 14
// baseline (223.296 us; speedup 1.0000x reference)
//
#include <hip/hip_runtime.h>
#include <stdint.h>

#define B_ 2
#define S_ 2048
#define D_ 2048
#define NH 16
#define NKV 4
#define HD_ 128

typedef unsigned short u16;
typedef unsigned int u32;
typedef __attribute__((ext_vector_type(8))) __bf16 bf16x8;
typedef __attribute__((ext_vector_type(4))) float f32x4;
typedef __attribute__((ext_vector_type(16))) float f32x16;
typedef __attribute__((ext_vector_type(4))) unsigned int u32x4;
typedef __attribute__((ext_vector_type(8))) unsigned short ushort8v;

__device__ __forceinline__ u16 f2bf(float f) {
  u32 u = __builtin_bit_cast(u32, f);
  u32 r = (u + 0x7FFFu + ((u >> 16) & 1u)) >> 16;  // RNE
  return (u16)r;
}
__device__ __forceinline__ float bf2f(u16 h) {
  return __builtin_bit_cast(float, ((u32)h) << 16);
}
__device__ __forceinline__ u32 cvtpk(float lo, float hi) {
  u32 r;
  asm("v_cvt_pk_bf16_f32 %0, %1, %2" : "=v"(r) : "v"(lo), "v"(hi));
  return r;
}
__device__ __forceinline__ float fexp2(float x) {  // bare v_exp_f32 (base-2)
  float r;
  asm("v_exp_f32 %0, %1" : "=v"(r) : "v"(x));
  return r;
}
__device__ __forceinline__ f32x16 zero16() {
  f32x16 v;
#pragma unroll
  for (int i = 0; i < 16; ++i) v[i] = 0.f;
  return v;
}

__device__ __forceinline__ void gld_lds16(const void* g, void* l) {
  __builtin_amdgcn_global_load_lds(
      (const __attribute__((address_space(1))) void*)g,
      (__attribute__((address_space(3))) void*)l, 16, 0, 0);
}

#define QSCALE 0.12750527540095196f  // 1/sqrt(128) * log2(e)

// ---------------- fp32 -> bf16 convert (x only; weights fused into GEMMs) ---
__global__ __launch_bounds__(256) void k_f2b_x(const float* __restrict__ x,
                                               u16* __restrict__ xb) {
  int i = blockIdx.x * 256 + threadIdx.x;  // 1048576 groups of 8
  const float4* sp = (const float4*)x + 2 * (size_t)i;
  float4 a = sp[0], b = sp[1];
  ushort8v o;
  o[0] = f2bf(a.x); o[1] = f2bf(a.y); o[2] = f2bf(a.z); o[3] = f2bf(a.w);
  o[4] = f2bf(b.x); o[5] = f2bf(b.y); o[6] = f2bf(b.z); o[7] = f2bf(b.w);
  *((ushort8v*)xb + i) = o;
}

// ------- GEMM (qkv): 256x128 tile, 8 waves, dbuf, 1-barrier + RoPE epi -----
// A: bf16 [256][128B] tiles. B: *** fp32 weights staged directly *** as
// [128][256B] tiles (4-bit XOR swizzle), converted bf16 at fragment load
// (2x ds_read_b128 + 4x v_cvt_pk). LDS 2x64KB = 128KB.
// by<16 -> Q head by (rope*QSCALE), by<20 -> K head by-16 (rope), else V copy.
__global__ __launch_bounds__(512, 1) void k_gemm_qkv(const u16* __restrict__ A,
    const float* __restrict__ Wq, const float* __restrict__ Wk,
    const float* __restrict__ Wv, u16* __restrict__ Qd, u16* __restrict__ Kd,
    u16* __restrict__ Vd, const float* __restrict__ fc,
    const float* __restrict__ fs, int K) {
  __shared__ char lds[2][65536];   // per buf: A bf16 32KB @0, B fp32 32KB @32768
  const int tid = threadIdx.x, lane = tid & 63, wave = tid >> 6;
  const int wm = wave >> 2, wn = wave & 3;
  const int m0 = blockIdx.x * 256, n0 = blockIdx.y * 128;
  const int by = blockIdx.y;
  const size_t Kb2 = (size_t)K * 2;
  const float* Wrow0 = (by < 16) ? Wq + (size_t)n0 * K
                      : (by < 20) ? Wk + (size_t)(n0 - 2048) * K
                                  : Wv + (size_t)(n0 - 2560) * K;
  f32x4 acc[8][2];
#pragma unroll
  for (int mi = 0; mi < 8; ++mi)
#pragma unroll
    for (int ni = 0; ni < 2; ++ni) acc[mi][ni] = f32x4{0.f, 0.f, 0.f, 0.f};
  int rA[4], cA[4], rB[4], cB[4];
#pragma unroll
  for (int j = 0; j < 4; ++j) {
    int p = j * 8192 + tid * 16;
    int o = p ^ (((p >> 7) & 7) << 4);
    rA[j] = o >> 7; cA[j] = o & 127;
    int ob = p ^ (((p >> 8) & 15) << 4);   // B: 256B rows, 4-bit involution
    rB[j] = ob >> 8; cB[j] = ob & 255;
  }
  auto stage = [&](int t) {
    char* dst = &lds[t & 1][0];
    const char* As = (const char*)A + (size_t)t * 128;
    const char* Ws = (const char*)Wrow0 + (size_t)t * 256;
#pragma unroll
    for (int j = 0; j < 4; ++j)
      gld_lds16(As + (size_t)(m0 + rA[j]) * Kb2 + cA[j], dst + j * 8192 + tid * 16);
#pragma unroll
    for (int j = 0; j < 4; ++j)
      gld_lds16(Ws + (size_t)rB[j] * K * 4 + cB[j], dst + 32768 + j * 8192 + tid * 16);
  };
  stage(0);
  __syncthreads();
  const int nt = K >> 6;
  for (int t = 0; t < nt; ++t) {
    if (t + 1 < nt) stage(t + 1);
    const char* buf = &lds[t & 1][0];
#pragma unroll
    for (int kk = 0; kk < 2; ++kk) {
      const int cb = kk * 64 + ((lane >> 4) << 4);
      bf16x8 af[8], bfr[2];
#pragma unroll
      for (int mi = 0; mi < 8; ++mi) {
        int r = wm * 128 + mi * 16 + (lane & 15);
        af[mi] = *(const bf16x8*)(buf + (r << 7) + (cb ^ ((r & 7) << 4)));
      }
#pragma unroll
      for (int ni = 0; ni < 2; ++ni) {
        int r = wn * 32 + ni * 16 + (lane & 15);
        int sw = (r & 15) << 4;
        int b0 = 2 * cb;                    // fp32 byte offset (multiple of 32)
        const char* bbp = buf + 32768 + (r << 8);
        f32x4 lo = *(const f32x4*)(bbp + (b0 ^ sw));
        f32x4 hi = *(const f32x4*)(bbp + ((b0 + 16) ^ sw));
        bfr[ni] = __builtin_bit_cast(bf16x8,
            u32x4{cvtpk(lo[0], lo[1]), cvtpk(lo[2], lo[3]),
                  cvtpk(hi[0], hi[1]), cvtpk(hi[2], hi[3])});
      }
      __builtin_amdgcn_s_setprio(1);
#pragma unroll
      for (int mi = 0; mi < 8; ++mi)
#pragma unroll
        for (int ni = 0; ni < 2; ++ni)
          acc[mi][ni] = __builtin_amdgcn_mfma_f32_16x16x32_bf16(af[mi], bfr[ni], acc[mi][ni], 0, 0, 0);
      __builtin_amdgcn_s_setprio(0);
    }
    __syncthreads();
  }
  // ---- fused RoPE/relayout epilogue ----
  const int seg = by;
  const int bb = m0 >> 11;
  if (seg < 20) {  // Q or K: rope
    const bool isQ = (seg < 16);
    const int h = isQ ? seg : seg - 16;
    u16* dstB = isQ ? (Qd + ((size_t)(bb * NH + h)) * S_ * HD_)
                    : (Kd + ((size_t)(bb * NKV + h)) * S_ * HD_);
    const float sc = isQ ? QSCALE : 1.0f;
#pragma unroll
    for (int ni = 0; ni < 2; ++ni) {
      const int c = (n0 + wn * 32 + ni * 16 + (lane & 15)) & 127;  // col in head
      const int j = c >> 1;
#pragma unroll
      for (int mi = 0; mi < 8; ++mi)
#pragma unroll
        for (int r = 0; r < 4; ++r) {
          const int m = m0 + wm * 128 + mi * 16 + ((lane >> 4) << 2) + r;
          const int s = m & 2047;
          float val = acc[mi][ni][r];
          float par = __shfl_xor(val, 1);
          float cs = fc[s * 64 + j], sn = fs[s * 64 + j];
          float outv = (c & 1) ? (par * sn + val * cs) : (val * cs - par * sn);
          dstB[(size_t)s * HD_ + c] = f2bf(outv * sc);
        }
    }
  } else {  // V: plain relayout
    const int h = seg - 20;
    u16* dstB = Vd + ((size_t)(bb * NKV + h)) * S_ * HD_;
#pragma unroll
    for (int ni = 0; ni < 2; ++ni) {
      const int c = (n0 + wn * 32 + ni * 16 + (lane & 15)) & 127;
#pragma unroll
      for (int mi = 0; mi < 8; ++mi)
#pragma unroll
        for (int r = 0; r < 4; ++r) {
          const int m = m0 + wm * 128 + mi * 16 + ((lane >> 4) << 2) + r;
          const int s = m & 2047;
          dstB[(size_t)s * HD_ + c] = f2bf(acc[mi][ni][r]);
        }
    }
  }
}

// ------- GEMM (out): 256x128, 8 waves, dbuf, 1-barrier; W = fp32 wo --------
__global__ __launch_bounds__(512, 1) void k_gemm_out(const u16* __restrict__ A,
    const float* __restrict__ W, float* __restrict__ C, int N, int K) {
  __shared__ char lds[2][65536];   // per buf: A bf16 32KB, B fp32 32KB
  const int tid = threadIdx.x, lane = tid & 63, wave = tid >> 6;
  const int wm = wave >> 2, wn = wave & 3;
  const int m0 = blockIdx.x * 256, n0 = blockIdx.y * 128;
  const size_t Kb2 = (size_t)K * 2;
  const float* Wrow0 = W + (size_t)n0 * K;
  f32x4 acc[8][2];
#pragma unroll
  for (int mi = 0; mi < 8; ++mi)
#pragma unroll
    for (int ni = 0; ni < 2; ++ni) acc[mi][ni] = f32x4{0.f, 0.f, 0.f, 0.f};
  int rA[4], cA[4], rB[4], cB[4];
#pragma unroll
  for (int j = 0; j < 4; ++j) {
    int p = j * 8192 + tid * 16;
    int o = p ^ (((p >> 7) & 7) << 4);
    rA[j] = o >> 7; cA[j] = o & 127;
    int ob = p ^ (((p >> 8) & 15) << 4);
    rB[j] = ob >> 8; cB[j] = ob & 255;
  }
  auto stage = [&](int t) {
    char* dst = &lds[t & 1][0];
    const char* As = (const char*)A + (size_t)t * 128;
    const char* Ws = (const char*)Wrow0 + (size_t)t * 256;
#pragma unroll
    for (int j = 0; j < 4; ++j)
      gld_lds16(As + (size_t)(m0 + rA[j]) * Kb2 + cA[j], dst + j * 8192 + tid * 16);
#pragma unroll
    for (int j = 0; j < 4; ++j)
      gld_lds16(Ws + (size_t)rB[j] * K * 4 + cB[j], dst + 32768 + j * 8192 + tid * 16);
  };
  stage(0);
  __syncthreads();
  const int nt = K >> 6;
  for (int t = 0; t < nt; ++t) {
    if (t + 1 < nt) stage(t + 1);
    const char* buf = &lds[t & 1][0];
#pragma unroll
    for (int kk = 0; kk < 2; ++kk) {
      const int cb = kk * 64 + ((lane >> 4) << 4);
      bf16x8 af[8], bfr[2];
#pragma unroll
      for (int mi = 0; mi < 8; ++mi) {
        int r = wm * 128 + mi * 16 + (lane & 15);
        af[mi] = *(const bf16x8*)(buf + (r << 7) + (cb ^ ((r & 7) << 4)));
      }
#pragma unroll
      for (int ni = 0; ni < 2; ++ni) {
        int r = wn * 32 + ni * 16 + (lane & 15);
        int sw = (r & 15) << 4;
        int b0 = 2 * cb;
        const char* bbp = buf + 32768 + (r << 8);
        f32x4 lo = *(const f32x4*)(bbp + (b0 ^ sw));
        f32x4 hi = *(const f32x4*)(bbp + ((b0 + 16) ^ sw));
        bfr[ni] = __builtin_bit_cast(bf16x8,
            u32x4{cvtpk(lo[0], lo[1]), cvtpk(lo[2], lo[3]),
                  cvtpk(hi[0], hi[1]), cvtpk(hi[2], hi[3])});
      }
      __builtin_amdgcn_s_setprio(1);
#pragma unroll
      for (int mi = 0; mi < 8; ++mi)
#pragma unroll
        for (int ni = 0; ni < 2; ++ni)
          acc[mi][ni] = __builtin_amdgcn_mfma_f32_16x16x32_bf16(af[mi], bfr[ni], acc[mi][ni], 0, 0, 0);
      __builtin_amdgcn_s_setprio(0);
    }
    __syncthreads();
  }
#pragma unroll
  for (int mi = 0; mi < 8; ++mi)
#pragma unroll
    for (int ni = 0; ni < 2; ++ni) {
      const int n = n0 + wn * 32 + ni * 16 + (lane & 15);
#pragma unroll
      for (int r = 0; r < 4; ++r) {
        const int m = m0 + wm * 128 + mi * 16 + ((lane >> 4) << 2) + r;
        C[(size_t)m * N + n] = acc[mi][ni][r];
      }
    }
}

// ---------------- causal GQA flash attention (R13 structure) ----------------
__global__ __launch_bounds__(256, 2) void k_attn(const u16* __restrict__ Q,
    const u16* __restrict__ Kt, const u16* __restrict__ Vt, u16* __restrict__ O) {
  __shared__ char kls[2][16384];   // K tile [64][256B], XOR-swizzled (4-bit)
  __shared__ char vls[2][16384];   // V^T tile [128 hd][128B kv], XOR-swizzled (3-bit)
  const int h = blockIdx.x, b = blockIdx.y;
  const int z = blockIdx.z;
  const int qtb = (z < 8) ? (15 - z) : (z - 8);  // heavy+light CU pairing
  const int tid = threadIdx.x, lane = tid & 63, wave = tid >> 6;
  const int ql = lane & 31, g = lane >> 5;
  const int kvh = h >> 2;
  const u16* Qb = Q + ((size_t)(b * NH + h)) * S_ * HD_;
  const u16* Kb = Kt + ((size_t)(b * NKV + kvh)) * S_ * HD_;
  const u16* Vb = Vt + ((size_t)(b * NKV + kvh)) * S_ * HD_;
  const int q0 = qtb * 128, qw0 = q0 + wave * 32;
  const int qme = qw0 + ql;
  int kRowS[4], kColS[4];
#pragma unroll
  for (int j = 0; j < 4; ++j) {
    int plin = j * 4096 + tid * 16;
    int o = plin ^ (((plin >> 8) & 15) << 4);   // 4-bit involution (bits 8-11 -> 4-7)
    kRowS[j] = o >> 8;
    kColS[j] = o & 255;
  }
  const int kp = tid & 31, hb = (tid >> 5) * 16;
  auto loadV = [&](int tn, u32* vr0, u32* vr1) {
    const u16* vp = Vb + (size_t)(tn * 64 + 2 * kp) * HD_ + hb;
    const u32* r0 = (const u32*)vp;
    const u32* r1 = (const u32*)(vp + HD_);
#pragma unroll
    for (int wd = 0; wd < 8; ++wd) { vr0[wd] = r0[wd]; vr1[wd] = r1[wd]; }
  };
  auto writeV = [&](char* vn, const u32* vr0, const u32* vr1) {
#pragma unroll
    for (int wd = 0; wd < 8; ++wd) {
      u32 v0 = vr0[wd], v1 = vr1[wd];
      u32 lo = (v0 & 0xFFFFu) | (v1 << 16);
      u32 hi = (v0 >> 16) | (v1 & 0xFFFF0000u);
      int hd0 = hb + 2 * wd, hd1 = hd0 + 1;
      *(u32*)(vn + hd0 * 128 + ((4 * kp) ^ ((hd0 & 7) << 4))) = lo;
      *(u32*)(vn + hd1 * 128 + ((4 * kp) ^ ((hd1 & 7) << 4))) = hi;
    }
  };

  // ---- prologue: stage K(0) + V(0); load Q fragments ----
#pragma unroll
  for (int j = 0; j < 4; ++j)
    gld_lds16((const char*)Kb + (size_t)kRowS[j] * 256 + kColS[j],
              &kls[0][0] + j * 4096 + wave * 1024);
  u32 pv0[8], pv1[8];
  loadV(0, pv0, pv1);
  bf16x8 qf[8];
#pragma unroll
  for (int kk = 0; kk < 8; ++kk)
    qf[kk] = *(const bf16x8*)(Qb + (size_t)qme * HD_ + kk * 16 + g * 8);
  writeV(&vls[0][0], pv0, pv1);
  __syncthreads();

  f32x16 oacc[4];
#pragma unroll
  for (int th = 0; th < 4; ++th) oacc[th] = zero16();
  float mrun = -1e30f, lrun = 0.0f;
  const int nt = 2 * qtb + 2;

  int cur = 0;
  for (int t = 0; t < nt; ++t) {
    const int kv0 = t * 64;
    const bool haveNext = (t + 1 < nt);
    u32 vr0[8], vr1[8];
    if (haveNext) {
      const int kvn = kv0 + 64;
#pragma unroll
      for (int j = 0; j < 4; ++j)
        gld_lds16((const char*)Kb + (size_t)(kvn + kRowS[j]) * 256 + kColS[j],
                  &kls[cur ^ 1][0] + j * 4096 + wave * 1024);
      loadV(t + 1, vr0, vr1);
    }
    if (kv0 <= qw0 + 31) {
      const char* kcur = &kls[cur][0];
      const char* vcur = &vls[cur][0];
      f32x16 c0 = zero16(), c1 = zero16();
      __builtin_amdgcn_s_setprio(1);
#pragma unroll
      for (int kk = 0; kk < 8; ++kk) {
        const int sw = (kk * 32 + 16 * g) ^ ((ql & 15) << 4);
        bf16x8 kf0 = *(const bf16x8*)(kcur + (ql << 8) + sw);
        bf16x8 kf1 = *(const bf16x8*)(kcur + ((32 + ql) << 8) + sw);
        c0 = __builtin_amdgcn_mfma_f32_32x32x16_bf16(kf0, qf[kk], c0, 0, 0, 0);
        c1 = __builtin_amdgcn_mfma_f32_32x32x16_bf16(kf1, qf[kk], c1, 0, 0, 0);
      }
      __builtin_amdgcn_s_setprio(0);
      const bool diag = (kv0 + 63 > qw0);
      float mt = -1e30f;
      if (diag) {
#pragma unroll
        for (int r = 0; r < 16; ++r) {
          float s0 = c0[r], s1 = c1[r];
          int kb = kv0 + (r & 3) + ((r >> 2) << 3) + 4 * g;
          if (kb > qme) s0 = -1e30f;
          if (kb + 32 > qme) s1 = -1e30f;
          c0[r] = s0; c1[r] = s1;
          mt = fmaxf(mt, fmaxf(s0, s1));
        }
      } else {
#pragma unroll
        for (int r = 0; r < 16; ++r)
          mt = fmaxf(mt, fmaxf(c0[r], c1[r]));
      }
      mt = fmaxf(mt, __shfl_xor(mt, 32));
      if (!__all(mt <= mrun + 8.0f)) {
        float mnew = fmaxf(mrun, mt);
        float alpha = fexp2(mrun - mnew);
        lrun *= alpha;
        mrun = mnew;
#pragma unroll
        for (int r = 0; r < 16; ++r) {
          float av = __shfl(alpha, 36 * g + (r & 3) + ((r >> 2) << 3));
          oacc[0][r] *= av; oacc[1][r] *= av;
          oacc[2][r] *= av; oacc[3][r] *= av;
        }
      }
      float lt = 0.0f;
#pragma unroll
      for (int r = 0; r < 16; ++r) {
        float p0 = fexp2(c0[r] - mrun);
        float p1 = fexp2(c1[r] - mrun);
        c0[r] = p0; c1[r] = p1;
        lt += p0 + p1;
      }
      lt += __shfl_xor(lt, 32);
      lrun += lt;
      u32 paw[4][4];
#pragma unroll
      for (int a = 0; a < 2; ++a) {
        {
          u32 X = cvtpk(c0[8 * a + 0], c0[8 * a + 1]);
          u32 Y = cvtpk(c0[8 * a + 2], c0[8 * a + 3]);
          u32 Z = cvtpk(c0[8 * a + 4], c0[8 * a + 5]);
          u32 W = cvtpk(c0[8 * a + 6], c0[8 * a + 7]);
          u32 S1 = g ? X : Z, S2 = g ? Y : W;
          u32 R1 = (u32)__shfl_xor((int)S1, 32), R2 = (u32)__shfl_xor((int)S2, 32);
          paw[a][0] = g ? R1 : X; paw[a][1] = g ? R2 : Y;
          paw[a][2] = g ? Z : R1; paw[a][3] = g ? W : R2;
        }
        {
          u32 X = cvtpk(c1[8 * a + 0], c1[8 * a + 1]);
          u32 Y = cvtpk(c1[8 * a + 2], c1[8 * a + 3]);
          u32 Z = cvtpk(c1[8 * a + 4], c1[8 * a + 5]);
          u32 W = cvtpk(c1[8 * a + 6], c1[8 * a + 7]);
          u32 S1 = g ? X : Z, S2 = g ? Y : W;
          u32 R1 = (u32)__shfl_xor((int)S1, 32), R2 = (u32)__shfl_xor((int)S2, 32);
          paw[2 + a][0] = g ? R1 : X; paw[2 + a][1] = g ? R2 : Y;
          paw[2 + a][2] = g ? Z : R1; paw[2 + a][3] = g ? W : R2;
        }
      }
      __builtin_amdgcn_s_setprio(1);
#pragma unroll
      for (int ks = 0; ks < 4; ++ks) {
        bf16x8 pf = __builtin_bit_cast(bf16x8,
            u32x4{paw[ks][0], paw[ks][1], paw[ks][2], paw[ks][3]});
        const int cb = (32 * ks + 16 * g) ^ ((ql & 7) << 4);
#pragma unroll
        for (int th = 0; th < 4; ++th) {
          bf16x8 vf = *(const bf16x8*)(vcur + ((th * 32 + ql) << 7) + cb);
          oacc[th] = __builtin_amdgcn_mfma_f32_32x32x16_bf16(pf, vf, oacc[th], 0, 0, 0);
        }
      }
      __builtin_amdgcn_s_setprio(0);
    }
    if (haveNext) writeV(&vls[cur ^ 1][0], vr0, vr1);
    __syncthreads();
    cur ^= 1;
  }
#pragma unroll
  for (int r = 0; r < 16; ++r) {
    float lr = __shfl(lrun, 36 * g + (r & 3) + ((r >> 2) << 3));
    float li = 1.0f / lr;
    int q = qw0 + (r & 3) + ((r >> 2) << 3) + 4 * g;
    size_t rowo = (size_t)(b * S_ + q) * D_ + h * HD_ + ql;
#pragma unroll
    for (int th = 0; th < 4; ++th)
      O[rowo + 32 * th] = f2bf(oacc[th][r] * li);
  }
}

// ---------------- launcher ----------------
// ws layout (60 MB):
//  [ 0,16) xb  -> attb (xb dead after gemm_qkv)
//  [36,52) Qb   [52,56) Kb   [56,60) Vb
extern "C" void kernel_launch(void* const* d_in, const int* in_sizes, int n_in,
                              void* d_out, int out_size, void* d_ws, size_t ws_size,
                              hipStream_t stream) {
  const float* x  = (const float*)d_in[0];
  const float* wq = (const float*)d_in[1];
  const float* wk = (const float*)d_in[2];
  const float* wv = (const float*)d_in[3];
  const float* wo = (const float*)d_in[4];
  const float* fc = (const float*)d_in[5];
  const float* fs = (const float*)d_in[6];
  float* out = (float*)d_out;
  char* ws = (char*)d_ws;
  const size_t MB = 1ull << 20;
  u16* xb   = (u16*)(ws);
  u16* Qb   = (u16*)(ws + 36 * MB);
  u16* Kb   = (u16*)(ws + 52 * MB);
  u16* Vb   = (u16*)(ws + 56 * MB);
  u16* attb = (u16*)(ws);                     // alias xb (dead after gemm_qkv)

  // x convert: 1,048,576 groups of 8 -> 4096 blocks
  k_f2b_x<<<dim3(4096), dim3(256), 0, stream>>>(x, xb);

  // QKV GEMM (256x128 dbuf, fp32-W fused convert) + RoPE/relayout epilogue
  k_gemm_qkv<<<dim3(16, 24), dim3(512), 0, stream>>>(xb, wq, wk, wv, Qb, Kb, Vb,
                                                     fc, fs, D_);

  k_attn<<<dim3(NH, B_, 16), dim3(256), 0, stream>>>(Qb, Kb, Vb, attb);

  // out GEMM (fp32-W fused convert)
  k_gemm_out<<<dim3(16, 16), dim3(512), 0, stream>>>(attb, wo, out, D_, D_);
}

// Round 15
// 207.394 us; speedup vs baseline: 1.0767x; 1.0767x over previous
//
#include <hip/hip_runtime.h>
#include <stdint.h>

#define B_ 2
#define S_ 2048
#define D_ 2048
#define NH 16
#define NKV 4
#define HD_ 128

typedef unsigned short u16;
typedef unsigned int u32;
typedef __attribute__((ext_vector_type(8))) __bf16 bf16x8;
typedef __attribute__((ext_vector_type(4))) float f32x4;
typedef __attribute__((ext_vector_type(16))) float f32x16;
typedef __attribute__((ext_vector_type(4))) unsigned int u32x4;
typedef __attribute__((ext_vector_type(8))) unsigned short ushort8v;

__device__ __forceinline__ u16 f2bf(float f) {
  u32 u = __builtin_bit_cast(u32, f);
  u32 r = (u + 0x7FFFu + ((u >> 16) & 1u)) >> 16;  // RNE
  return (u16)r;
}
__device__ __forceinline__ float bf2f(u16 h) {
  return __builtin_bit_cast(float, ((u32)h) << 16);
}
__device__ __forceinline__ u32 cvtpk(float lo, float hi) {
  u32 r;
  asm("v_cvt_pk_bf16_f32 %0, %1, %2" : "=v"(r) : "v"(lo), "v"(hi));
  return r;
}
__device__ __forceinline__ float fexp2(float x) {  // bare v_exp_f32 (base-2)
  float r;
  asm("v_exp_f32 %0, %1" : "=v"(r) : "v"(x));
  return r;
}
__device__ __forceinline__ f32x16 zero16() {
  f32x16 v;
#pragma unroll
  for (int i = 0; i < 16; ++i) v[i] = 0.f;
  return v;
}

__device__ __forceinline__ void gld_lds16(const void* g, void* l) {
  __builtin_amdgcn_global_load_lds(
      (const __attribute__((address_space(1))) void*)g,
      (__attribute__((address_space(3))) void*)l, 16, 0, 0);
}

#define QSCALE 0.12750527540095196f  // 1/sqrt(128) * log2(e)

// ---------------- fp32 -> bf16 convert (all 5 tensors, one launch) ----------
__device__ __forceinline__ void cv8(const float* s, u16* d, int i) {
  const float4* sp = (const float4*)s + 2 * (size_t)i;
  float4 a = sp[0], b = sp[1];
  ushort8v o;
  o[0] = f2bf(a.x); o[1] = f2bf(a.y); o[2] = f2bf(a.z); o[3] = f2bf(a.w);
  o[4] = f2bf(b.x); o[5] = f2bf(b.y); o[6] = f2bf(b.z); o[7] = f2bf(b.w);
  *((ushort8v*)d + i) = o;
}
// segments (groups of 8): x 1048576 | wq 524288 | wk 131072 | wv 131072 | wo 524288
// total 2359296 -> 9216 blocks of 256
__global__ __launch_bounds__(256) void k_f2b_all(const float* __restrict__ x,
    const float* __restrict__ wq, const float* __restrict__ wk,
    const float* __restrict__ wv, const float* __restrict__ wo,
    u16* __restrict__ xb, u16* __restrict__ wqkv, u16* __restrict__ wob) {
  int i = blockIdx.x * 256 + threadIdx.x;
  if (i < 1048576) { cv8(x, xb, i); return; }
  i -= 1048576;
  if (i < 524288) { cv8(wq, wqkv, i); return; }
  i -= 524288;
  if (i < 131072) { cv8(wk, wqkv + 2048 * 2048, i); return; }
  i -= 131072;
  if (i < 131072) { cv8(wv, wqkv + 2560 * 2048, i); return; }
  i -= 131072;
  if (i < 524288) cv8(wo, wob, i);
}

// ------- GEMM (qkv): 256x128 tile, 8 waves, dbuf, 1-barrier + RoPE epi -----
// bf16 W (proven R12 config). by<16 -> Q head by (rope*QSCALE), by<20 -> K
// head by-16 (rope), else V copy. Rope pairs in adjacent lanes (shfl_xor 1).
__global__ __launch_bounds__(512, 1) void k_gemm_qkv(const u16* __restrict__ A,
    const u16* __restrict__ W, u16* __restrict__ Qd, u16* __restrict__ Kd,
    u16* __restrict__ Vd, const float* __restrict__ fc,
    const float* __restrict__ fs, int K) {
  __shared__ char lds[2][49152];   // per buf: A[256][64] @0 (32KB), B[128][64] @32768 (16KB)
  const int tid = threadIdx.x, lane = tid & 63, wave = tid >> 6;
  const int wm = wave >> 2, wn = wave & 3;
  const int m0 = blockIdx.x * 256, n0 = blockIdx.y * 128;
  const int by = blockIdx.y;
  const size_t Kb2 = (size_t)K * 2;
  f32x4 acc[8][2];
#pragma unroll
  for (int mi = 0; mi < 8; ++mi)
#pragma unroll
    for (int ni = 0; ni < 2; ++ni) acc[mi][ni] = f32x4{0.f, 0.f, 0.f, 0.f};
  int rA[4], cA[4], rB[2], cB[2];
#pragma unroll
  for (int j = 0; j < 4; ++j) {
    int p = j * 8192 + tid * 16;
    int o = p ^ (((p >> 7) & 7) << 4);
    rA[j] = o >> 7; cA[j] = o & 127;
  }
#pragma unroll
  for (int j = 0; j < 2; ++j) {
    int p = j * 8192 + tid * 16;
    int o = p ^ (((p >> 7) & 7) << 4);
    rB[j] = o >> 7; cB[j] = o & 127;
  }
  auto stage = [&](int t) {
    char* dst = &lds[t & 1][0];
    const char* As = (const char*)A + (size_t)t * 128;
    const char* Ws = (const char*)W + (size_t)t * 128;
#pragma unroll
    for (int j = 0; j < 4; ++j)
      gld_lds16(As + (size_t)(m0 + rA[j]) * Kb2 + cA[j], dst + j * 8192 + tid * 16);
#pragma unroll
    for (int j = 0; j < 2; ++j)
      gld_lds16(Ws + (size_t)(n0 + rB[j]) * Kb2 + cB[j], dst + 32768 + j * 8192 + tid * 16);
  };
  stage(0);
  __syncthreads();
  const int nt = K >> 6;
  for (int t = 0; t < nt; ++t) {
    if (t + 1 < nt) stage(t + 1);
    const char* buf = &lds[t & 1][0];
#pragma unroll
    for (int kk = 0; kk < 2; ++kk) {
      const int cb = kk * 64 + ((lane >> 4) << 4);
      bf16x8 af[8], bfr[2];
#pragma unroll
      for (int mi = 0; mi < 8; ++mi) {
        int r = wm * 128 + mi * 16 + (lane & 15);
        af[mi] = *(const bf16x8*)(buf + (r << 7) + (cb ^ ((r & 7) << 4)));
      }
#pragma unroll
      for (int ni = 0; ni < 2; ++ni) {
        int r = wn * 32 + ni * 16 + (lane & 15);
        bfr[ni] = *(const bf16x8*)(buf + 32768 + (r << 7) + (cb ^ ((r & 7) << 4)));
      }
      __builtin_amdgcn_s_setprio(1);
#pragma unroll
      for (int mi = 0; mi < 8; ++mi)
#pragma unroll
        for (int ni = 0; ni < 2; ++ni)
          acc[mi][ni] = __builtin_amdgcn_mfma_f32_16x16x32_bf16(af[mi], bfr[ni], acc[mi][ni], 0, 0, 0);
      __builtin_amdgcn_s_setprio(0);
    }
    __syncthreads();
  }
  // ---- fused RoPE/relayout epilogue ----
  const int seg = by;
  const int bb = m0 >> 11;
  if (seg < 20) {  // Q or K: rope
    const bool isQ = (seg < 16);
    const int h = isQ ? seg : seg - 16;
    u16* dstB = isQ ? (Qd + ((size_t)(bb * NH + h)) * S_ * HD_)
                    : (Kd + ((size_t)(bb * NKV + h)) * S_ * HD_);
    const float sc = isQ ? QSCALE : 1.0f;
#pragma unroll
    for (int ni = 0; ni < 2; ++ni) {
      const int c = (n0 + wn * 32 + ni * 16 + (lane & 15)) & 127;  // col in head
      const int j = c >> 1;
#pragma unroll
      for (int mi = 0; mi < 8; ++mi)
#pragma unroll
        for (int r = 0; r < 4; ++r) {
          const int m = m0 + wm * 128 + mi * 16 + ((lane >> 4) << 2) + r;
          const int s = m & 2047;
          float val = acc[mi][ni][r];
          float par = __shfl_xor(val, 1);
          float cs = fc[s * 64 + j], sn = fs[s * 64 + j];
          float outv = (c & 1) ? (par * sn + val * cs) : (val * cs - par * sn);
          dstB[(size_t)s * HD_ + c] = f2bf(outv * sc);
        }
    }
  } else {  // V: plain relayout
    const int h = seg - 20;
    u16* dstB = Vd + ((size_t)(bb * NKV + h)) * S_ * HD_;
#pragma unroll
    for (int ni = 0; ni < 2; ++ni) {
      const int c = (n0 + wn * 32 + ni * 16 + (lane & 15)) & 127;
#pragma unroll
      for (int mi = 0; mi < 8; ++mi)
#pragma unroll
        for (int r = 0; r < 4; ++r) {
          const int m = m0 + wm * 128 + mi * 16 + ((lane >> 4) << 2) + r;
          const int s = m & 2047;
          dstB[(size_t)s * HD_ + c] = f2bf(acc[mi][ni][r]);
        }
    }
  }
}

// ---------------- GEMM (out): 256x128 tile, 8 waves, dbuf, 1-barrier -------
__global__ __launch_bounds__(512, 1) void k_gemm_out(const u16* __restrict__ A,
    const u16* __restrict__ W, float* __restrict__ C, int N, int K) {
  __shared__ char lds[2][49152];
  const int tid = threadIdx.x, lane = tid & 63, wave = tid >> 6;
  const int wm = wave >> 2, wn = wave & 3;
  const int m0 = blockIdx.x * 256, n0 = blockIdx.y * 128;
  const size_t Kb2 = (size_t)K * 2;
  f32x4 acc[8][2];
#pragma unroll
  for (int mi = 0; mi < 8; ++mi)
#pragma unroll
    for (int ni = 0; ni < 2; ++ni) acc[mi][ni] = f32x4{0.f, 0.f, 0.f, 0.f};
  int rA[4], cA[4], rB[2], cB[2];
#pragma unroll
  for (int j = 0; j < 4; ++j) {
    int p = j * 8192 + tid * 16;
    int o = p ^ (((p >> 7) & 7) << 4);
    rA[j] = o >> 7; cA[j] = o & 127;
  }
#pragma unroll
  for (int j = 0; j < 2; ++j) {
    int p = j * 8192 + tid * 16;
    int o = p ^ (((p >> 7) & 7) << 4);
    rB[j] = o >> 7; cB[j] = o & 127;
  }
  auto stage = [&](int t) {
    char* dst = &lds[t & 1][0];
    const char* As = (const char*)A + (size_t)t * 128;
    const char* Ws = (const char*)W + (size_t)t * 128;
#pragma unroll
    for (int j = 0; j < 4; ++j)
      gld_lds16(As + (size_t)(m0 + rA[j]) * Kb2 + cA[j], dst + j * 8192 + tid * 16);
#pragma unroll
    for (int j = 0; j < 2; ++j)
      gld_lds16(Ws + (size_t)(n0 + rB[j]) * Kb2 + cB[j], dst + 32768 + j * 8192 + tid * 16);
  };
  stage(0);
  __syncthreads();
  const int nt = K >> 6;
  for (int t = 0; t < nt; ++t) {
    if (t + 1 < nt) stage(t + 1);
    const char* buf = &lds[t & 1][0];
#pragma unroll
    for (int kk = 0; kk < 2; ++kk) {
      const int cb = kk * 64 + ((lane >> 4) << 4);
      bf16x8 af[8], bfr[2];
#pragma unroll
      for (int mi = 0; mi < 8; ++mi) {
        int r = wm * 128 + mi * 16 + (lane & 15);
        af[mi] = *(const bf16x8*)(buf + (r << 7) + (cb ^ ((r & 7) << 4)));
      }
#pragma unroll
      for (int ni = 0; ni < 2; ++ni) {
        int r = wn * 32 + ni * 16 + (lane & 15);
        bfr[ni] = *(const bf16x8*)(buf + 32768 + (r << 7) + (cb ^ ((r & 7) << 4)));
      }
      __builtin_amdgcn_s_setprio(1);
#pragma unroll
      for (int mi = 0; mi < 8; ++mi)
#pragma unroll
        for (int ni = 0; ni < 2; ++ni)
          acc[mi][ni] = __builtin_amdgcn_mfma_f32_16x16x32_bf16(af[mi], bfr[ni], acc[mi][ni], 0, 0, 0);
      __builtin_amdgcn_s_setprio(0);
    }
    __syncthreads();
  }
#pragma unroll
  for (int mi = 0; mi < 8; ++mi)
#pragma unroll
    for (int ni = 0; ni < 2; ++ni) {
      const int n = n0 + wn * 32 + ni * 16 + (lane & 15);
#pragma unroll
      for (int r = 0; r < 4; ++r) {
        const int m = m0 + wm * 128 + mi * 16 + ((lane >> 4) << 2) + r;
        C[(size_t)m * N + n] = acc[mi][ni][r];
      }
    }
}

// ---------------- causal GQA flash attention (R13 structure + tree reduce) --
__global__ __launch_bounds__(256, 2) void k_attn(const u16* __restrict__ Q,
    const u16* __restrict__ Kt, const u16* __restrict__ Vt, u16* __restrict__ O) {
  __shared__ char kls[2][16384];   // K tile [64][256B], XOR-swizzled (4-bit)
  __shared__ char vls[2][16384];   // V^T tile [128 hd][128B kv], XOR-swizzled (3-bit)
  const int h = blockIdx.x, b = blockIdx.y;
  const int z = blockIdx.z;
  const int qtb = (z < 8) ? (15 - z) : (z - 8);  // heavy+light CU pairing
  const int tid = threadIdx.x, lane = tid & 63, wave = tid >> 6;
  const int ql = lane & 31, g = lane >> 5;
  const int kvh = h >> 2;
  const u16* Qb = Q + ((size_t)(b * NH + h)) * S_ * HD_;
  const u16* Kb = Kt + ((size_t)(b * NKV + kvh)) * S_ * HD_;
  const u16* Vb = Vt + ((size_t)(b * NKV + kvh)) * S_ * HD_;
  const int q0 = qtb * 128, qw0 = q0 + wave * 32;
  const int qme = qw0 + ql;
  int kRowS[4], kColS[4];
#pragma unroll
  for (int j = 0; j < 4; ++j) {
    int plin = j * 4096 + tid * 16;
    int o = plin ^ (((plin >> 8) & 15) << 4);   // 4-bit involution (bits 8-11 -> 4-7)
    kRowS[j] = o >> 8;
    kColS[j] = o & 255;
  }
  const int kp = tid & 31, hb = (tid >> 5) * 16;
  auto loadV = [&](int tn, u32* vr0, u32* vr1) {
    const u16* vp = Vb + (size_t)(tn * 64 + 2 * kp) * HD_ + hb;
    const u32* r0 = (const u32*)vp;
    const u32* r1 = (const u32*)(vp + HD_);
#pragma unroll
    for (int wd = 0; wd < 8; ++wd) { vr0[wd] = r0[wd]; vr1[wd] = r1[wd]; }
  };
  auto writeV = [&](char* vn, const u32* vr0, const u32* vr1) {
#pragma unroll
    for (int wd = 0; wd < 8; ++wd) {
      u32 v0 = vr0[wd], v1 = vr1[wd];
      u32 lo = (v0 & 0xFFFFu) | (v1 << 16);
      u32 hi = (v0 >> 16) | (v1 & 0xFFFF0000u);
      int hd0 = hb + 2 * wd, hd1 = hd0 + 1;
      *(u32*)(vn + hd0 * 128 + ((4 * kp) ^ ((hd0 & 7) << 4))) = lo;
      *(u32*)(vn + hd1 * 128 + ((4 * kp) ^ ((hd1 & 7) << 4))) = hi;
    }
  };

  // ---- prologue: stage K(0) + V(0); load Q fragments ----
#pragma unroll
  for (int j = 0; j < 4; ++j)
    gld_lds16((const char*)Kb + (size_t)kRowS[j] * 256 + kColS[j],
              &kls[0][0] + j * 4096 + wave * 1024);
  u32 pv0[8], pv1[8];
  loadV(0, pv0, pv1);
  bf16x8 qf[8];
#pragma unroll
  for (int kk = 0; kk < 8; ++kk)
    qf[kk] = *(const bf16x8*)(Qb + (size_t)qme * HD_ + kk * 16 + g * 8);
  writeV(&vls[0][0], pv0, pv1);
  __syncthreads();

  f32x16 oacc[4];
#pragma unroll
  for (int th = 0; th < 4; ++th) oacc[th] = zero16();
  float mrun = -1e30f, lrun = 0.0f;
  const int nt = 2 * qtb + 2;

  int cur = 0;
  for (int t = 0; t < nt; ++t) {
    const int kv0 = t * 64;
    const bool haveNext = (t + 1 < nt);
    u32 vr0[8], vr1[8];
    if (haveNext) {
      const int kvn = kv0 + 64;
#pragma unroll
      for (int j = 0; j < 4; ++j)
        gld_lds16((const char*)Kb + (size_t)(kvn + kRowS[j]) * 256 + kColS[j],
                  &kls[cur ^ 1][0] + j * 4096 + wave * 1024);
      loadV(t + 1, vr0, vr1);
    }
    if (kv0 <= qw0 + 31) {
      const char* kcur = &kls[cur][0];
      const char* vcur = &vls[cur][0];
      f32x16 c0 = zero16(), c1 = zero16();
      __builtin_amdgcn_s_setprio(1);
#pragma unroll
      for (int kk = 0; kk < 8; ++kk) {
        const int sw = (kk * 32 + 16 * g) ^ ((ql & 15) << 4);
        bf16x8 kf0 = *(const bf16x8*)(kcur + (ql << 8) + sw);
        bf16x8 kf1 = *(const bf16x8*)(kcur + ((32 + ql) << 8) + sw);
        c0 = __builtin_amdgcn_mfma_f32_32x32x16_bf16(kf0, qf[kk], c0, 0, 0, 0);
        c1 = __builtin_amdgcn_mfma_f32_32x32x16_bf16(kf1, qf[kk], c1, 0, 0, 0);
      }
      __builtin_amdgcn_s_setprio(0);
      const bool diag = (kv0 + 63 > qw0);
      // 4-way split max (breaks the 32-deep dependent fmax chain; pairs fuse
      // to v_max3 on the combine)
      float m0x = -1e30f, m1x = -1e30f, m2x = -1e30f, m3x = -1e30f;
      if (diag) {
#pragma unroll
        for (int r = 0; r < 16; r += 4) {
          float s00 = c0[r],     s01 = c0[r + 1], s02 = c0[r + 2], s03 = c0[r + 3];
          float s10 = c1[r],     s11 = c1[r + 1], s12 = c1[r + 2], s13 = c1[r + 3];
          int kb0 = kv0 + ((r >> 2) << 3) + 4 * g;
          if (kb0 + 0 > qme) s00 = -1e30f;
          if (kb0 + 1 > qme) s01 = -1e30f;
          if (kb0 + 2 > qme) s02 = -1e30f;
          if (kb0 + 3 > qme) s03 = -1e30f;
          if (kb0 + 32 > qme) s10 = -1e30f;
          if (kb0 + 33 > qme) s11 = -1e30f;
          if (kb0 + 34 > qme) s12 = -1e30f;
          if (kb0 + 35 > qme) s13 = -1e30f;
          c0[r] = s00; c0[r + 1] = s01; c0[r + 2] = s02; c0[r + 3] = s03;
          c1[r] = s10; c1[r + 1] = s11; c1[r + 2] = s12; c1[r + 3] = s13;
          m0x = fmaxf(m0x, fmaxf(s00, s10));
          m1x = fmaxf(m1x, fmaxf(s01, s11));
          m2x = fmaxf(m2x, fmaxf(s02, s12));
          m3x = fmaxf(m3x, fmaxf(s03, s13));
        }
      } else {
#pragma unroll
        for (int r = 0; r < 16; r += 4) {
          m0x = fmaxf(m0x, fmaxf(c0[r], c1[r]));
          m1x = fmaxf(m1x, fmaxf(c0[r + 1], c1[r + 1]));
          m2x = fmaxf(m2x, fmaxf(c0[r + 2], c1[r + 2]));
          m3x = fmaxf(m3x, fmaxf(c0[r + 3], c1[r + 3]));
        }
      }
      float mt = fmaxf(fmaxf(m0x, m1x), fmaxf(m2x, m3x));
      mt = fmaxf(mt, __shfl_xor(mt, 32));
      if (!__all(mt <= mrun + 8.0f)) {
        float mnew = fmaxf(mrun, mt);
        float alpha = fexp2(mrun - mnew);
        lrun *= alpha;
        mrun = mnew;
#pragma unroll
        for (int r = 0; r < 16; ++r) {
          float av = __shfl(alpha, 36 * g + (r & 3) + ((r >> 2) << 3));
          oacc[0][r] *= av; oacc[1][r] *= av;
          oacc[2][r] *= av; oacc[3][r] *= av;
        }
      }
      // 4-way split sum
      float l0 = 0.f, l1 = 0.f, l2 = 0.f, l3 = 0.f;
#pragma unroll
      for (int r = 0; r < 16; r += 4) {
        float p00 = fexp2(c0[r] - mrun),     p01 = fexp2(c0[r + 1] - mrun);
        float p02 = fexp2(c0[r + 2] - mrun), p03 = fexp2(c0[r + 3] - mrun);
        float p10 = fexp2(c1[r] - mrun),     p11 = fexp2(c1[r + 1] - mrun);
        float p12 = fexp2(c1[r + 2] - mrun), p13 = fexp2(c1[r + 3] - mrun);
        c0[r] = p00; c0[r + 1] = p01; c0[r + 2] = p02; c0[r + 3] = p03;
        c1[r] = p10; c1[r + 1] = p11; c1[r + 2] = p12; c1[r + 3] = p13;
        l0 += p00 + p10; l1 += p01 + p11; l2 += p02 + p12; l3 += p03 + p13;
      }
      float lt = (l0 + l1) + (l2 + l3);
      lt += __shfl_xor(lt, 32);
      lrun += lt;
      u32 paw[4][4];
#pragma unroll
      for (int a = 0; a < 2; ++a) {
        {
          u32 X = cvtpk(c0[8 * a + 0], c0[8 * a + 1]);
          u32 Y = cvtpk(c0[8 * a + 2], c0[8 * a + 3]);
          u32 Z = cvtpk(c0[8 * a + 4], c0[8 * a + 5]);
          u32 W = cvtpk(c0[8 * a + 6], c0[8 * a + 7]);
          u32 S1 = g ? X : Z, S2 = g ? Y : W;
          u32 R1 = (u32)__shfl_xor((int)S1, 32), R2 = (u32)__shfl_xor((int)S2, 32);
          paw[a][0] = g ? R1 : X; paw[a][1] = g ? R2 : Y;
          paw[a][2] = g ? Z : R1; paw[a][3] = g ? W : R2;
        }
        {
          u32 X = cvtpk(c1[8 * a + 0], c1[8 * a + 1]);
          u32 Y = cvtpk(c1[8 * a + 2], c1[8 * a + 3]);
          u32 Z = cvtpk(c1[8 * a + 4], c1[8 * a + 5]);
          u32 W = cvtpk(c1[8 * a + 6], c1[8 * a + 7]);
          u32 S1 = g ? X : Z, S2 = g ? Y : W;
          u32 R1 = (u32)__shfl_xor((int)S1, 32), R2 = (u32)__shfl_xor((int)S2, 32);
          paw[2 + a][0] = g ? R1 : X; paw[2 + a][1] = g ? R2 : Y;
          paw[2 + a][2] = g ? Z : R1; paw[2 + a][3] = g ? W : R2;
        }
      }
      __builtin_amdgcn_s_setprio(1);
#pragma unroll
      for (int ks = 0; ks < 4; ++ks) {
        bf16x8 pf = __builtin_bit_cast(bf16x8,
            u32x4{paw[ks][0], paw[ks][1], paw[ks][2], paw[ks][3]});
        const int cb = (32 * ks + 16 * g) ^ ((ql & 7) << 4);
#pragma unroll
        for (int th = 0; th < 4; ++th) {
          bf16x8 vf = *(const bf16x8*)(vcur + ((th * 32 + ql) << 7) + cb);
          oacc[th] = __builtin_amdgcn_mfma_f32_32x32x16_bf16(pf, vf, oacc[th], 0, 0, 0);
        }
      }
      __builtin_amdgcn_s_setprio(0);
    }
    if (haveNext) writeV(&vls[cur ^ 1][0], vr0, vr1);
    __syncthreads();
    cur ^= 1;
  }
#pragma unroll
  for (int r = 0; r < 16; ++r) {
    float lr = __shfl(lrun, 36 * g + (r & 3) + ((r >> 2) << 3));
    float li = 1.0f / lr;
    int q = qw0 + (r & 3) + ((r >> 2) << 3) + 4 * g;
    size_t rowo = (size_t)(b * S_ + q) * D_ + h * HD_ + ql;
#pragma unroll
    for (int th = 0; th < 4; ++th)
      O[rowo + 32 * th] = f2bf(oacc[th][r] * li);
  }
}

// ---------------- launcher ----------------
// ws layout (60 MB):
//  [ 0,16) xb  -> attb (xb dead after gemm_qkv)
//  [16,28) wqkv (dead after gemm_qkv)
//  [28,36) wob
//  [36,52) Qb   [52,56) Kb   [56,60) Vb
extern "C" void kernel_launch(void* const* d_in, const int* in_sizes, int n_in,
                              void* d_out, int out_size, void* d_ws, size_t ws_size,
                              hipStream_t stream) {
  const float* x  = (const float*)d_in[0];
  const float* wq = (const float*)d_in[1];
  const float* wk = (const float*)d_in[2];
  const float* wv = (const float*)d_in[3];
  const float* wo = (const float*)d_in[4];
  const float* fc = (const float*)d_in[5];
  const float* fs = (const float*)d_in[6];
  float* out = (float*)d_out;
  char* ws = (char*)d_ws;
  const size_t MB = 1ull << 20;
  u16* xb   = (u16*)(ws);
  u16* wqkv = (u16*)(ws + 16 * MB);
  u16* wob  = (u16*)(ws + 28 * MB);
  u16* Qb   = (u16*)(ws + 36 * MB);
  u16* Kb   = (u16*)(ws + 52 * MB);
  u16* Vb   = (u16*)(ws + 56 * MB);
  u16* attb = (u16*)(ws);                     // alias xb (dead after gemm_qkv)

  // converts: 2,359,296 groups of 8 -> 9216 blocks
  k_f2b_all<<<dim3(9216), dim3(256), 0, stream>>>(x, wq, wk, wv, wo, xb, wqkv, wob);

  // QKV GEMM (256x128 dbuf) with fused RoPE + head-major relayout epilogue
  k_gemm_qkv<<<dim3(16, 24), dim3(512), 0, stream>>>(xb, wqkv, Qb, Kb, Vb, fc, fs, D_);

  k_attn<<<dim3(NH, B_, 16), dim3(256), 0, stream>>>(Qb, Kb, Vb, attb);

  k_gemm_out<<<dim3(16, 16), dim3(512), 0, stream>>>(attb, wob, out, D_, D_);
}

// Round 16
// 190.592 us; speedup vs baseline: 1.1716x; 1.0882x over previous
//
#include <hip/hip_runtime.h>
#include <stdint.h>

#define B_ 2
#define S_ 2048
#define D_ 2048
#define NH 16
#define NKV 4
#define HD_ 128

typedef unsigned short u16;
typedef unsigned int u32;
typedef __attribute__((ext_vector_type(8))) __bf16 bf16x8;
typedef __attribute__((ext_vector_type(4))) float f32x4;
typedef __attribute__((ext_vector_type(16))) float f32x16;
typedef __attribute__((ext_vector_type(4))) unsigned int u32x4;
typedef __attribute__((ext_vector_type(8))) unsigned short ushort8v;

__device__ __forceinline__ u16 f2bf(float f) {
  u32 u = __builtin_bit_cast(u32, f);
  u32 r = (u + 0x7FFFu + ((u >> 16) & 1u)) >> 16;  // RNE
  return (u16)r;
}
__device__ __forceinline__ float bf2f(u16 h) {
  return __builtin_bit_cast(float, ((u32)h) << 16);
}
__device__ __forceinline__ u32 cvtpk(float lo, float hi) {
  u32 r;
  asm("v_cvt_pk_bf16_f32 %0, %1, %2" : "=v"(r) : "v"(lo), "v"(hi));
  return r;
}
__device__ __forceinline__ float fexp2(float x) {  // bare v_exp_f32 (base-2)
  float r;
  asm("v_exp_f32 %0, %1" : "=v"(r) : "v"(x));
  return r;
}
__device__ __forceinline__ f32x16 zero16() {
  f32x16 v;
#pragma unroll
  for (int i = 0; i < 16; ++i) v[i] = 0.f;
  return v;
}

__device__ __forceinline__ void gld_lds16(const void* g, void* l) {
  __builtin_amdgcn_global_load_lds(
      (const __attribute__((address_space(1))) void*)g,
      (__attribute__((address_space(3))) void*)l, 16, 0, 0);
}

#define QSCALE 0.12750527540095196f  // 1/sqrt(128) * log2(e)

// ---------------- fp32 -> bf16 convert (all 5 tensors, one launch) ----------
__device__ __forceinline__ void cv8(const float* s, u16* d, int i) {
  const float4* sp = (const float4*)s + 2 * (size_t)i;
  float4 a = sp[0], b = sp[1];
  ushort8v o;
  o[0] = f2bf(a.x); o[1] = f2bf(a.y); o[2] = f2bf(a.z); o[3] = f2bf(a.w);
  o[4] = f2bf(b.x); o[5] = f2bf(b.y); o[6] = f2bf(b.z); o[7] = f2bf(b.w);
  *((ushort8v*)d + i) = o;
}
// segments (groups of 8): x 1048576 | wq 524288 | wk 131072 | wv 131072 | wo 524288
// total 2359296 -> 9216 blocks of 256
__global__ __launch_bounds__(256) void k_f2b_all(const float* __restrict__ x,
    const float* __restrict__ wq, const float* __restrict__ wk,
    const float* __restrict__ wv, const float* __restrict__ wo,
    u16* __restrict__ xb, u16* __restrict__ wqkv, u16* __restrict__ wob) {
  int i = blockIdx.x * 256 + threadIdx.x;
  if (i < 1048576) { cv8(x, xb, i); return; }
  i -= 1048576;
  if (i < 524288) { cv8(wq, wqkv, i); return; }
  i -= 524288;
  if (i < 131072) { cv8(wk, wqkv + 2048 * 2048, i); return; }
  i -= 131072;
  if (i < 131072) { cv8(wv, wqkv + 2560 * 2048, i); return; }
  i -= 131072;
  if (i < 524288) cv8(wo, wob, i);
}

// ------- GEMM (qkv): 256x192 tile, 8 waves, dbuf, 1-barrier + RoPE epi -----
// Grid (16,16) = 256 blocks = EXACTLY one dispatch round (was 384 = 1.5
// rounds -> 2-round makespan, 25% idle). 192-col tiles span 1.5 heads, so
// the epilogue decodes segment/head per 16-col fragment from the absolute
// column (fragment-uniform: 128 % 16 == 0). Rope pairs stay lane-adjacent.
__global__ __launch_bounds__(512, 1) void k_gemm_qkv(const u16* __restrict__ A,
    const u16* __restrict__ W, u16* __restrict__ Qd, u16* __restrict__ Kd,
    u16* __restrict__ Vd, const float* __restrict__ fc,
    const float* __restrict__ fs, int K) {
  __shared__ char lds[2][57344];   // per buf: A[256][128B] 32KB @0, B[192][128B] 24KB @32768
  const int tid = threadIdx.x, lane = tid & 63, wave = tid >> 6;
  const int wm = wave >> 2, wn = wave & 3;
  const int m0 = blockIdx.x * 256, n0 = blockIdx.y * 192;
  const size_t Kb2 = (size_t)K * 2;
  f32x4 acc[8][3];
#pragma unroll
  for (int mi = 0; mi < 8; ++mi)
#pragma unroll
    for (int ni = 0; ni < 3; ++ni) acc[mi][ni] = f32x4{0.f, 0.f, 0.f, 0.f};
  int rA[4], cA[4], rB[3], cB[3];
#pragma unroll
  for (int j = 0; j < 4; ++j) {
    int p = j * 8192 + tid * 16;
    int o = p ^ (((p >> 7) & 7) << 4);
    rA[j] = o >> 7; cA[j] = o & 127;
  }
#pragma unroll
  for (int j = 0; j < 3; ++j) {
    int p = j * 8192 + tid * 16;
    int o = p ^ (((p >> 7) & 7) << 4);
    rB[j] = o >> 7; cB[j] = o & 127;
  }
  auto stage = [&](int t) {
    char* dst = &lds[t & 1][0];
    const char* As = (const char*)A + (size_t)t * 128;
    const char* Ws = (const char*)W + (size_t)t * 128;
#pragma unroll
    for (int j = 0; j < 4; ++j)
      gld_lds16(As + (size_t)(m0 + rA[j]) * Kb2 + cA[j], dst + j * 8192 + tid * 16);
#pragma unroll
    for (int j = 0; j < 3; ++j)
      gld_lds16(Ws + (size_t)(n0 + rB[j]) * Kb2 + cB[j], dst + 32768 + j * 8192 + tid * 16);
  };
  stage(0);
  __syncthreads();
  const int nt = K >> 6;
  for (int t = 0; t < nt; ++t) {
    if (t + 1 < nt) stage(t + 1);
    const char* buf = &lds[t & 1][0];
#pragma unroll
    for (int kk = 0; kk < 2; ++kk) {
      const int cb = kk * 64 + ((lane >> 4) << 4);
      bf16x8 af[8], bfr[3];
#pragma unroll
      for (int mi = 0; mi < 8; ++mi) {
        int r = wm * 128 + mi * 16 + (lane & 15);
        af[mi] = *(const bf16x8*)(buf + (r << 7) + (cb ^ ((r & 7) << 4)));
      }
#pragma unroll
      for (int ni = 0; ni < 3; ++ni) {
        int r = wn * 48 + ni * 16 + (lane & 15);
        bfr[ni] = *(const bf16x8*)(buf + 32768 + (r << 7) + (cb ^ ((r & 7) << 4)));
      }
      __builtin_amdgcn_s_setprio(1);
#pragma unroll
      for (int mi = 0; mi < 8; ++mi)
#pragma unroll
        for (int ni = 0; ni < 3; ++ni)
          acc[mi][ni] = __builtin_amdgcn_mfma_f32_16x16x32_bf16(af[mi], bfr[ni], acc[mi][ni], 0, 0, 0);
      __builtin_amdgcn_s_setprio(0);
    }
    __syncthreads();
  }
  // ---- fused RoPE/relayout epilogue (per-fragment segment decode) ----
  const int bb = m0 >> 11;
#pragma unroll
  for (int ni = 0; ni < 3; ++ni) {
    const int ac = n0 + wn * 48 + ni * 16 + (lane & 15);  // abs col in [0,3072)
    const int c = ac & 127;                                // col within head
    if (ac < 2560) {  // Q or K: rope
      const bool isQ = (ac < 2048);
      const int h = isQ ? (ac >> 7) : ((ac - 2048) >> 7);
      u16* dstB = isQ ? (Qd + ((size_t)(bb * NH + h)) * S_ * HD_)
                      : (Kd + ((size_t)(bb * NKV + h)) * S_ * HD_);
      const float sc = isQ ? QSCALE : 1.0f;
      const int j = c >> 1;
#pragma unroll
      for (int mi = 0; mi < 8; ++mi)
#pragma unroll
        for (int r = 0; r < 4; ++r) {
          const int m = m0 + wm * 128 + mi * 16 + ((lane >> 4) << 2) + r;
          const int s = m & 2047;
          float val = acc[mi][ni][r];
          float par = __shfl_xor(val, 1);
          float cs = fc[s * 64 + j], sn = fs[s * 64 + j];
          float outv = (c & 1) ? (par * sn + val * cs) : (val * cs - par * sn);
          dstB[(size_t)s * HD_ + c] = f2bf(outv * sc);
        }
    } else {  // V: plain relayout
      const int h = (ac - 2560) >> 7;
      u16* dstB = Vd + ((size_t)(bb * NKV + h)) * S_ * HD_;
#pragma unroll
      for (int mi = 0; mi < 8; ++mi)
#pragma unroll
        for (int r = 0; r < 4; ++r) {
          const int m = m0 + wm * 128 + mi * 16 + ((lane >> 4) << 2) + r;
          const int s = m & 2047;
          dstB[(size_t)s * HD_ + c] = f2bf(acc[mi][ni][r]);
        }
    }
  }
}

// ---------------- GEMM (out): 256x128 tile, 8 waves, dbuf, 1-barrier -------
__global__ __launch_bounds__(512, 1) void k_gemm_out(const u16* __restrict__ A,
    const u16* __restrict__ W, float* __restrict__ C, int N, int K) {
  __shared__ char lds[2][49152];
  const int tid = threadIdx.x, lane = tid & 63, wave = tid >> 6;
  const int wm = wave >> 2, wn = wave & 3;
  const int m0 = blockIdx.x * 256, n0 = blockIdx.y * 128;
  const size_t Kb2 = (size_t)K * 2;
  f32x4 acc[8][2];
#pragma unroll
  for (int mi = 0; mi < 8; ++mi)
#pragma unroll
    for (int ni = 0; ni < 2; ++ni) acc[mi][ni] = f32x4{0.f, 0.f, 0.f, 0.f};
  int rA[4], cA[4], rB[2], cB[2];
#pragma unroll
  for (int j = 0; j < 4; ++j) {
    int p = j * 8192 + tid * 16;
    int o = p ^ (((p >> 7) & 7) << 4);
    rA[j] = o >> 7; cA[j] = o & 127;
  }
#pragma unroll
  for (int j = 0; j < 2; ++j) {
    int p = j * 8192 + tid * 16;
    int o = p ^ (((p >> 7) & 7) << 4);
    rB[j] = o >> 7; cB[j] = o & 127;
  }
  auto stage = [&](int t) {
    char* dst = &lds[t & 1][0];
    const char* As = (const char*)A + (size_t)t * 128;
    const char* Ws = (const char*)W + (size_t)t * 128;
#pragma unroll
    for (int j = 0; j < 4; ++j)
      gld_lds16(As + (size_t)(m0 + rA[j]) * Kb2 + cA[j], dst + j * 8192 + tid * 16);
#pragma unroll
    for (int j = 0; j < 2; ++j)
      gld_lds16(Ws + (size_t)(n0 + rB[j]) * Kb2 + cB[j], dst + 32768 + j * 8192 + tid * 16);
  };
  stage(0);
  __syncthreads();
  const int nt = K >> 6;
  for (int t = 0; t < nt; ++t) {
    if (t + 1 < nt) stage(t + 1);
    const char* buf = &lds[t & 1][0];
#pragma unroll
    for (int kk = 0; kk < 2; ++kk) {
      const int cb = kk * 64 + ((lane >> 4) << 4);
      bf16x8 af[8], bfr[2];
#pragma unroll
      for (int mi = 0; mi < 8; ++mi) {
        int r = wm * 128 + mi * 16 + (lane & 15);
        af[mi] = *(const bf16x8*)(buf + (r << 7) + (cb ^ ((r & 7) << 4)));
      }
#pragma unroll
      for (int ni = 0; ni < 2; ++ni) {
        int r = wn * 32 + ni * 16 + (lane & 15);
        bfr[ni] = *(const bf16x8*)(buf + 32768 + (r << 7) + (cb ^ ((r & 7) << 4)));
      }
      __builtin_amdgcn_s_setprio(1);
#pragma unroll
      for (int mi = 0; mi < 8; ++mi)
#pragma unroll
        for (int ni = 0; ni < 2; ++ni)
          acc[mi][ni] = __builtin_amdgcn_mfma_f32_16x16x32_bf16(af[mi], bfr[ni], acc[mi][ni], 0, 0, 0);
      __builtin_amdgcn_s_setprio(0);
    }
    __syncthreads();
  }
#pragma unroll
  for (int mi = 0; mi < 8; ++mi)
#pragma unroll
    for (int ni = 0; ni < 2; ++ni) {
      const int n = n0 + wn * 32 + ni * 16 + (lane & 15);
#pragma unroll
      for (int r = 0; r < 4; ++r) {
        const int m = m0 + wm * 128 + mi * 16 + ((lane >> 4) << 2) + r;
        C[(size_t)m * N + n] = acc[mi][ni][r];
      }
    }
}

// ---------------- causal GQA flash attention (R15 structure) ----------------
__global__ __launch_bounds__(256, 2) void k_attn(const u16* __restrict__ Q,
    const u16* __restrict__ Kt, const u16* __restrict__ Vt, u16* __restrict__ O) {
  __shared__ char kls[2][16384];   // K tile [64][256B], XOR-swizzled (4-bit)
  __shared__ char vls[2][16384];   // V^T tile [128 hd][128B kv], XOR-swizzled (3-bit)
  const int h = blockIdx.x, b = blockIdx.y;
  const int z = blockIdx.z;
  const int qtb = (z < 8) ? (15 - z) : (z - 8);  // heavy+light CU pairing
  const int tid = threadIdx.x, lane = tid & 63, wave = tid >> 6;
  const int ql = lane & 31, g = lane >> 5;
  const int kvh = h >> 2;
  const u16* Qb = Q + ((size_t)(b * NH + h)) * S_ * HD_;
  const u16* Kb = Kt + ((size_t)(b * NKV + kvh)) * S_ * HD_;
  const u16* Vb = Vt + ((size_t)(b * NKV + kvh)) * S_ * HD_;
  const int q0 = qtb * 128, qw0 = q0 + wave * 32;
  const int qme = qw0 + ql;
  int kRowS[4], kColS[4];
#pragma unroll
  for (int j = 0; j < 4; ++j) {
    int plin = j * 4096 + tid * 16;
    int o = plin ^ (((plin >> 8) & 15) << 4);   // 4-bit involution (bits 8-11 -> 4-7)
    kRowS[j] = o >> 8;
    kColS[j] = o & 255;
  }
  const int kp = tid & 31, hb = (tid >> 5) * 16;
  auto loadV = [&](int tn, u32* vr0, u32* vr1) {
    const u16* vp = Vb + (size_t)(tn * 64 + 2 * kp) * HD_ + hb;
    const u32* r0 = (const u32*)vp;
    const u32* r1 = (const u32*)(vp + HD_);
#pragma unroll
    for (int wd = 0; wd < 8; ++wd) { vr0[wd] = r0[wd]; vr1[wd] = r1[wd]; }
  };
  auto writeV = [&](char* vn, const u32* vr0, const u32* vr1) {
#pragma unroll
    for (int wd = 0; wd < 8; ++wd) {
      u32 v0 = vr0[wd], v1 = vr1[wd];
      u32 lo = (v0 & 0xFFFFu) | (v1 << 16);
      u32 hi = (v0 >> 16) | (v1 & 0xFFFF0000u);
      int hd0 = hb + 2 * wd, hd1 = hd0 + 1;
      *(u32*)(vn + hd0 * 128 + ((4 * kp) ^ ((hd0 & 7) << 4))) = lo;
      *(u32*)(vn + hd1 * 128 + ((4 * kp) ^ ((hd1 & 7) << 4))) = hi;
    }
  };

  // ---- prologue: stage K(0) + V(0); load Q fragments ----
#pragma unroll
  for (int j = 0; j < 4; ++j)
    gld_lds16((const char*)Kb + (size_t)kRowS[j] * 256 + kColS[j],
              &kls[0][0] + j * 4096 + wave * 1024);
  u32 pv0[8], pv1[8];
  loadV(0, pv0, pv1);
  bf16x8 qf[8];
#pragma unroll
  for (int kk = 0; kk < 8; ++kk)
    qf[kk] = *(const bf16x8*)(Qb + (size_t)qme * HD_ + kk * 16 + g * 8);
  writeV(&vls[0][0], pv0, pv1);
  __syncthreads();

  f32x16 oacc[4];
#pragma unroll
  for (int th = 0; th < 4; ++th) oacc[th] = zero16();
  float mrun = -1e30f, lrun = 0.0f;
  const int nt = 2 * qtb + 2;

  int cur = 0;
  for (int t = 0; t < nt; ++t) {
    const int kv0 = t * 64;
    const bool haveNext = (t + 1 < nt);
    u32 vr0[8], vr1[8];
    if (haveNext) {
      const int kvn = kv0 + 64;
#pragma unroll
      for (int j = 0; j < 4; ++j)
        gld_lds16((const char*)Kb + (size_t)(kvn + kRowS[j]) * 256 + kColS[j],
                  &kls[cur ^ 1][0] + j * 4096 + wave * 1024);
      loadV(t + 1, vr0, vr1);
    }
    if (kv0 <= qw0 + 31) {
      const char* kcur = &kls[cur][0];
      const char* vcur = &vls[cur][0];
      f32x16 c0 = zero16(), c1 = zero16();
      __builtin_amdgcn_s_setprio(1);
#pragma unroll
      for (int kk = 0; kk < 8; ++kk) {
        const int sw = (kk * 32 + 16 * g) ^ ((ql & 15) << 4);
        bf16x8 kf0 = *(const bf16x8*)(kcur + (ql << 8) + sw);
        bf16x8 kf1 = *(const bf16x8*)(kcur + ((32 + ql) << 8) + sw);
        c0 = __builtin_amdgcn_mfma_f32_32x32x16_bf16(kf0, qf[kk], c0, 0, 0, 0);
        c1 = __builtin_amdgcn_mfma_f32_32x32x16_bf16(kf1, qf[kk], c1, 0, 0, 0);
      }
      __builtin_amdgcn_s_setprio(0);
      const bool diag = (kv0 + 63 > qw0);
      float m0x = -1e30f, m1x = -1e30f, m2x = -1e30f, m3x = -1e30f;
      if (diag) {
#pragma unroll
        for (int r = 0; r < 16; r += 4) {
          float s00 = c0[r],     s01 = c0[r + 1], s02 = c0[r + 2], s03 = c0[r + 3];
          float s10 = c1[r],     s11 = c1[r + 1], s12 = c1[r + 2], s13 = c1[r + 3];
          int kb0 = kv0 + ((r >> 2) << 3) + 4 * g;
          if (kb0 + 0 > qme) s00 = -1e30f;
          if (kb0 + 1 > qme) s01 = -1e30f;
          if (kb0 + 2 > qme) s02 = -1e30f;
          if (kb0 + 3 > qme) s03 = -1e30f;
          if (kb0 + 32 > qme) s10 = -1e30f;
          if (kb0 + 33 > qme) s11 = -1e30f;
          if (kb0 + 34 > qme) s12 = -1e30f;
          if (kb0 + 35 > qme) s13 = -1e30f;
          c0[r] = s00; c0[r + 1] = s01; c0[r + 2] = s02; c0[r + 3] = s03;
          c1[r] = s10; c1[r + 1] = s11; c1[r + 2] = s12; c1[r + 3] = s13;
          m0x = fmaxf(m0x, fmaxf(s00, s10));
          m1x = fmaxf(m1x, fmaxf(s01, s11));
          m2x = fmaxf(m2x, fmaxf(s02, s12));
          m3x = fmaxf(m3x, fmaxf(s03, s13));
        }
      } else {
#pragma unroll
        for (int r = 0; r < 16; r += 4) {
          m0x = fmaxf(m0x, fmaxf(c0[r], c1[r]));
          m1x = fmaxf(m1x, fmaxf(c0[r + 1], c1[r + 1]));
          m2x = fmaxf(m2x, fmaxf(c0[r + 2], c1[r + 2]));
          m3x = fmaxf(m3x, fmaxf(c0[r + 3], c1[r + 3]));
        }
      }
      float mt = fmaxf(fmaxf(m0x, m1x), fmaxf(m2x, m3x));
      mt = fmaxf(mt, __shfl_xor(mt, 32));
      if (!__all(mt <= mrun + 8.0f)) {
        float mnew = fmaxf(mrun, mt);
        float alpha = fexp2(mrun - mnew);
        lrun *= alpha;
        mrun = mnew;
#pragma unroll
        for (int r = 0; r < 16; ++r) {
          float av = __shfl(alpha, 36 * g + (r & 3) + ((r >> 2) << 3));
          oacc[0][r] *= av; oacc[1][r] *= av;
          oacc[2][r] *= av; oacc[3][r] *= av;
        }
      }
      float l0 = 0.f, l1 = 0.f, l2 = 0.f, l3 = 0.f;
#pragma unroll
      for (int r = 0; r < 16; r += 4) {
        float p00 = fexp2(c0[r] - mrun),     p01 = fexp2(c0[r + 1] - mrun);
        float p02 = fexp2(c0[r + 2] - mrun), p03 = fexp2(c0[r + 3] - mrun);
        float p10 = fexp2(c1[r] - mrun),     p11 = fexp2(c1[r + 1] - mrun);
        float p12 = fexp2(c1[r + 2] - mrun), p13 = fexp2(c1[r + 3] - mrun);
        c0[r] = p00; c0[r + 1] = p01; c0[r + 2] = p02; c0[r + 3] = p03;
        c1[r] = p10; c1[r + 1] = p11; c1[r + 2] = p12; c1[r + 3] = p13;
        l0 += p00 + p10; l1 += p01 + p11; l2 += p02 + p12; l3 += p03 + p13;
      }
      float lt = (l0 + l1) + (l2 + l3);
      lt += __shfl_xor(lt, 32);
      lrun += lt;
      u32 paw[4][4];
#pragma unroll
      for (int a = 0; a < 2; ++a) {
        {
          u32 X = cvtpk(c0[8 * a + 0], c0[8 * a + 1]);
          u32 Y = cvtpk(c0[8 * a + 2], c0[8 * a + 3]);
          u32 Z = cvtpk(c0[8 * a + 4], c0[8 * a + 5]);
          u32 W = cvtpk(c0[8 * a + 6], c0[8 * a + 7]);
          u32 S1 = g ? X : Z, S2 = g ? Y : W;
          u32 R1 = (u32)__shfl_xor((int)S1, 32), R2 = (u32)__shfl_xor((int)S2, 32);
          paw[a][0] = g ? R1 : X; paw[a][1] = g ? R2 : Y;
          paw[a][2] = g ? Z : R1; paw[a][3] = g ? W : R2;
        }
        {
          u32 X = cvtpk(c1[8 * a + 0], c1[8 * a + 1]);
          u32 Y = cvtpk(c1[8 * a + 2], c1[8 * a + 3]);
          u32 Z = cvtpk(c1[8 * a + 4], c1[8 * a + 5]);
          u32 W = cvtpk(c1[8 * a + 6], c1[8 * a + 7]);
          u32 S1 = g ? X : Z, S2 = g ? Y : W;
          u32 R1 = (u32)__shfl_xor((int)S1, 32), R2 = (u32)__shfl_xor((int)S2, 32);
          paw[2 + a][0] = g ? R1 : X; paw[2 + a][1] = g ? R2 : Y;
          paw[2 + a][2] = g ? Z : R1; paw[2 + a][3] = g ? W : R2;
        }
      }
      __builtin_amdgcn_s_setprio(1);
#pragma unroll
      for (int ks = 0; ks < 4; ++ks) {
        bf16x8 pf = __builtin_bit_cast(bf16x8,
            u32x4{paw[ks][0], paw[ks][1], paw[ks][2], paw[ks][3]});
        const int cb = (32 * ks + 16 * g) ^ ((ql & 7) << 4);
#pragma unroll
        for (int th = 0; th < 4; ++th) {
          bf16x8 vf = *(const bf16x8*)(vcur + ((th * 32 + ql) << 7) + cb);
          oacc[th] = __builtin_amdgcn_mfma_f32_32x32x16_bf16(pf, vf, oacc[th], 0, 0, 0);
        }
      }
      __builtin_amdgcn_s_setprio(0);
    }
    if (haveNext) writeV(&vls[cur ^ 1][0], vr0, vr1);
    __syncthreads();
    cur ^= 1;
  }
#pragma unroll
  for (int r = 0; r < 16; ++r) {
    float lr = __shfl(lrun, 36 * g + (r & 3) + ((r >> 2) << 3));
    float li = 1.0f / lr;
    int q = qw0 + (r & 3) + ((r >> 2) << 3) + 4 * g;
    size_t rowo = (size_t)(b * S_ + q) * D_ + h * HD_ + ql;
#pragma unroll
    for (int th = 0; th < 4; ++th)
      O[rowo + 32 * th] = f2bf(oacc[th][r] * li);
  }
}

// ---------------- launcher ----------------
// ws layout (60 MB):
//  [ 0,16) xb  -> attb (xb dead after gemm_qkv)
//  [16,28) wqkv (dead after gemm_qkv)
//  [28,36) wob
//  [36,52) Qb   [52,56) Kb   [56,60) Vb
extern "C" void kernel_launch(void* const* d_in, const int* in_sizes, int n_in,
                              void* d_out, int out_size, void* d_ws, size_t ws_size,
                              hipStream_t stream) {
  const float* x  = (const float*)d_in[0];
  const float* wq = (const float*)d_in[1];
  const float* wk = (const float*)d_in[2];
  const float* wv = (const float*)d_in[3];
  const float* wo = (const float*)d_in[4];
  const float* fc = (const float*)d_in[5];
  const float* fs = (const float*)d_in[6];
  float* out = (float*)d_out;
  char* ws = (char*)d_ws;
  const size_t MB = 1ull << 20;
  u16* xb   = (u16*)(ws);
  u16* wqkv = (u16*)(ws + 16 * MB);
  u16* wob  = (u16*)(ws + 28 * MB);
  u16* Qb   = (u16*)(ws + 36 * MB);
  u16* Kb   = (u16*)(ws + 52 * MB);
  u16* Vb   = (u16*)(ws + 56 * MB);
  u16* attb = (u16*)(ws);                     // alias xb (dead after gemm_qkv)

  // converts: 2,359,296 groups of 8 -> 9216 blocks
  k_f2b_all<<<dim3(9216), dim3(256), 0, stream>>>(x, wq, wk, wv, wo, xb, wqkv, wob);

  // QKV GEMM (256x192 dbuf, one full dispatch round) + RoPE/relayout epilogue
  k_gemm_qkv<<<dim3(16, 16), dim3(512), 0, stream>>>(xb, wqkv, Qb, Kb, Vb, fc, fs, D_);

  k_attn<<<dim3(NH, B_, 16), dim3(256), 0, stream>>>(Qb, Kb, Vb, attb);

  k_gemm_out<<<dim3(16, 16), dim3(512), 0, stream>>>(attb, wob, out, D_, D_);
}